// Round 3
// baseline (682.537 us; speedup 1.0000x reference)
//
#include <hip/hip_runtime.h>
#include <math.h>

// Fused: L2-normalize(emb row) -> sim[row] = scale * <emb_n[row], d*summary[seg[row]]>
//
// R3: (R2 was ~150us main kernel vs ~60-85us memory floor; latency-bound)
//  - one prep kernel (sd = summary*d*scale  +  seg scatter)
//  - main: 2 row-groups per thread (wave covers 16 rows) -> 2x in-flight
//    loads per wave, hides the seg->w dependent chain
//  - packed {dot,sumsq} 64-bit shuffle reduce: 3 steps instead of 6

#define HDIM 128
#define NEPS 1e-12f

// ---- prep: sd row + seg scatter, one block per segment ----
__global__ void prep(const int* __restrict__ ptr,
                     const float* __restrict__ summary,
                     const float* __restrict__ dvec,
                     const float* __restrict__ scale,
                     float* __restrict__ sd, int* __restrict__ seg) {
    const int s  = blockIdx.x;
    const float sc = scale[0];
    for (int h = threadIdx.x; h < HDIM; h += blockDim.x)
        sd[s * HDIM + h] = summary[s * HDIM + h] * dvec[h] * sc;
    const int lo = ptr[s], hi = ptr[s + 1];
    for (int i = lo + threadIdx.x; i < hi; i += blockDim.x)
        seg[i] = s;
}

__device__ inline float2 shfl_xor_f2(float2 v, int m) {
    union { double d; float2 f; } u;
    u.f = v;
    u.d = __shfl_xor(u.d, m, 64);
    return u.f;
}

// ---- main: 8 lanes/row, 2 row-groups per thread ----
__global__ __launch_bounds__(256) void sim_main(
    const float* __restrict__ emb,
    const float* __restrict__ sd,
    const int* __restrict__ seg,
    float* __restrict__ out, int N)
{
    const int tid  = blockIdx.x * blockDim.x + threadIdx.x;
    const int lane = tid & 63;
    const int sub  = lane & 7;       // lane within 8-lane row group
    const int grp  = lane >> 3;      // 0..7
    const long long wave = (long long)(tid >> 6);

    const long long r0 = wave * 16 + grp;       // first row-group
    const long long r1 = r0 + 8;                // second row-group
    if (r0 >= N) return;
    const bool has1 = (r1 < N);

    // seg loads for both groups issue first (independent)
    const int s0 = seg[r0];
    const int s1 = has1 ? seg[r1] : s0;

    const float4* e0 = (const float4*)(emb + r0 * HDIM);
    const float4* e1 = (const float4*)(emb + r1 * HDIM);
    const float4* w0 = (const float4*)(sd + (long long)s0 * HDIM);
    const float4* w1 = (const float4*)(sd + (long long)s1 * HDIM);

    float2 acc0 = {0.f, 0.f};   // x = dot, y = sumsq
    float2 acc1 = {0.f, 0.f};

    #pragma unroll
    for (int j = 0; j < 4; ++j) {
        const float4 a = e0[sub + 8 * j];
        const float4 b = w0[sub + 8 * j];
        acc0.x = fmaf(a.x, b.x, acc0.x); acc0.y = fmaf(a.x, a.x, acc0.y);
        acc0.x = fmaf(a.y, b.y, acc0.x); acc0.y = fmaf(a.y, a.y, acc0.y);
        acc0.x = fmaf(a.z, b.z, acc0.x); acc0.y = fmaf(a.z, a.z, acc0.y);
        acc0.x = fmaf(a.w, b.w, acc0.x); acc0.y = fmaf(a.w, a.w, acc0.y);
    }
    if (has1) {
        #pragma unroll
        for (int j = 0; j < 4; ++j) {
            const float4 a = e1[sub + 8 * j];
            const float4 b = w1[sub + 8 * j];
            acc1.x = fmaf(a.x, b.x, acc1.x); acc1.y = fmaf(a.x, a.x, acc1.y);
            acc1.x = fmaf(a.y, b.y, acc1.x); acc1.y = fmaf(a.y, a.y, acc1.y);
            acc1.x = fmaf(a.z, b.z, acc1.x); acc1.y = fmaf(a.z, a.z, acc1.y);
            acc1.x = fmaf(a.w, b.w, acc1.x); acc1.y = fmaf(a.w, a.w, acc1.y);
        }
    }

    // packed reduce across the 8-lane group (masks 4,2,1 stay in-group)
    #pragma unroll
    for (int m = 4; m >= 1; m >>= 1) {
        const float2 o0 = shfl_xor_f2(acc0, m);
        const float2 o1 = shfl_xor_f2(acc1, m);
        acc0.x += o0.x; acc0.y += o0.y;
        acc1.x += o1.x; acc1.y += o1.y;
    }

    if (sub == 0) {
        out[r0] = acc0.x / fmaxf(sqrtf(acc0.y), NEPS);
        if (has1)
            out[r1] = acc1.x / fmaxf(sqrtf(acc1.y), NEPS);
    }
}

// ---- fallback (no workspace): R1 kernel ----
__global__ __launch_bounds__(256) void sim_fallback(
    const float* __restrict__ emb, const float* __restrict__ summary,
    const int* __restrict__ ptr, const float* __restrict__ dvec,
    const float* __restrict__ scale, float* __restrict__ out, int N, int B)
{
    const int tid  = blockIdx.x * blockDim.x + threadIdx.x;
    const int lane = tid & 63;
    const int half = lane >> 5;
    const int l    = lane & 31;
    const long long row = (long long)(tid >> 6) * 2 + half;
    if (row >= N) return;
    int lo = 0, hi = B;
    while (lo < hi) {
        int mid = (lo + hi) >> 1;
        if (ptr[1 + mid] <= (int)row) lo = mid + 1; else hi = mid;
    }
    const float4* e4 = (const float4*)(emb + row * HDIM);
    const float4* s4 = (const float4*)(summary + (long long)lo * HDIM);
    const float4* d4 = (const float4*)dvec;
    const float4 e = e4[l], s = s4[l], dd = d4[l];
    float sumsq = e.x*e.x + e.y*e.y + e.z*e.z + e.w*e.w;
    float dot   = e.x*dd.x*s.x + e.y*dd.y*s.y + e.z*dd.z*s.z + e.w*dd.w*s.w;
    #pragma unroll
    for (int m = 16; m >= 1; m >>= 1) {
        sumsq += __shfl_xor(sumsq, m, 64);
        dot   += __shfl_xor(dot,   m, 64);
    }
    if (l == 0)
        out[row] = dot / fmaxf(sqrtf(sumsq), NEPS) * scale[0];
}

extern "C" void kernel_launch(void* const* d_in, const int* in_sizes, int n_in,
                              void* d_out, int out_size, void* d_ws, size_t ws_size,
                              hipStream_t stream) {
    const float* emb     = (const float*)d_in[0];
    const float* summary = (const float*)d_in[1];
    const int*   ptr     = (const int*)d_in[2];
    const float* dvec    = (const float*)d_in[3];
    const float* scale   = (const float*)d_in[4];
    float*       out     = (float*)d_out;

    const int Hn = in_sizes[3];           // 128
    const int N  = in_sizes[0] / Hn;      // 1048576
    const int B  = in_sizes[1] / Hn;      // 1024

    const size_t sd_bytes  = (size_t)B * Hn * sizeof(float);   // 512 KB
    const size_t seg_bytes = (size_t)N * sizeof(int);          // 4 MB

    if (ws_size >= sd_bytes + seg_bytes) {
        float* sd  = (float*)d_ws;
        int*   seg = (int*)((char*)d_ws + sd_bytes);

        prep<<<B, 256, 0, stream>>>(ptr, summary, dvec, scale, sd, seg);
        // 16 rows per wave, 4 waves per block -> 64 rows per block
        sim_main<<<(N + 63) / 64, 256, 0, stream>>>(emb, sd, seg, out, N);
    } else {
        sim_fallback<<<(N + 7) / 8, 256, 0, stream>>>(emb, summary, ptr, dvec,
                                                      scale, out, N, B);
    }
}

// Round 4
// 680.352 us; speedup vs baseline: 1.0032x; 1.0032x over previous
//
#include <hip/hip_runtime.h>
#include <math.h>

// Fused: L2-normalize(emb row) -> sim[row] = scale * <emb_n[row], d*summary[seg[row]]>
//
// R4: (R3 ILP doubling was NEUTRAL at ~159us pipeline vs ~70us floor ->
//      latency-hiding was not the limiter. New theory: the 8-lane-per-row
//      layout makes every vmem instruction touch 8 discontiguous 128B
//      segments. Switch to 32-lane-per-row: each load instr is 1KB fully
//      contiguous. Keep seg[] scatter table + prefolded sd = summary*d*scale.)
//   wave = 8 consecutive rows as 4 row-pairs; 8 independent 16B loads/thread.

#define HDIM 128
#define HD4  32          // float4s per row
#define NEPS 1e-12f

// ---- prep: sd row + seg scatter, one block per segment ----
__global__ void prep(const int* __restrict__ ptr,
                     const float* __restrict__ summary,
                     const float* __restrict__ dvec,
                     const float* __restrict__ scale,
                     float* __restrict__ sd, int* __restrict__ seg) {
    const int s  = blockIdx.x;
    const float sc = scale[0];
    for (int h = threadIdx.x; h < HDIM; h += blockDim.x)
        sd[s * HDIM + h] = summary[s * HDIM + h] * dvec[h] * sc;
    const int lo = ptr[s], hi = ptr[s + 1];
    for (int i = lo + threadIdx.x; i < hi; i += blockDim.x)
        seg[i] = s;
}

__device__ inline float2 shfl_xor_f2(float2 v, int m) {
    union { double d; float2 f; } u;
    u.f = v;
    u.d = __shfl_xor(u.d, m, 64);
    return u.f;
}

// ---- main: 32 lanes/row, 4 row-pairs per thread ----
__global__ __launch_bounds__(256) void sim_main(
    const float4* __restrict__ emb4,
    const float*  __restrict__ sd,
    const int*    __restrict__ seg,
    float*        __restrict__ out,
    int N)
{
    const int lane   = threadIdx.x & 63;
    const int wlocal = threadIdx.x >> 6;                    // 0..3
    const long long W = (long long)blockIdx.x * 4 + wlocal; // global wave id
    const long long rbase = W * 8;                          // 8 rows per wave
    if (rbase >= N) return;
    const int half = lane >> 5;
    const int col  = lane & 31;

    if (rbase + 8 <= N) {
        // ---- fast path: all loads contiguous, no guards ----
        float4 e[4];
        int    s[4];
        #pragma unroll
        for (int j = 0; j < 4; ++j) {
            e[j] = emb4[(rbase + 2 * j) * HD4 + lane];      // 1KB contiguous/instr
            s[j] = seg[rbase + 2 * j + half];               // broadcast per half
        }
        float4 w[4];
        #pragma unroll
        for (int j = 0; j < 4; ++j)
            w[j] = ((const float4*)sd)[(long long)s[j] * HD4 + col];

        #pragma unroll
        for (int j = 0; j < 4; ++j) {
            float2 acc;
            acc.x = e[j].x * w[j].x + e[j].y * w[j].y
                  + e[j].z * w[j].z + e[j].w * w[j].w;       // dot
            acc.y = e[j].x * e[j].x + e[j].y * e[j].y
                  + e[j].z * e[j].z + e[j].w * e[j].w;       // sumsq
            #pragma unroll
            for (int m = 16; m >= 1; m >>= 1) {
                const float2 o = shfl_xor_f2(acc, m);
                acc.x += o.x; acc.y += o.y;
            }
            const float res   = acc.x / fmaxf(sqrtf(acc.y), NEPS);
            const float other = __shfl_xor(res, 32, 64);
            if (lane == 0) {
                float2* o2 = (float2*)(out + rbase + 2 * j);
                *o2 = make_float2(res, other);
            }
        }
    } else {
        // ---- tail path: per-row guards ----
        #pragma unroll
        for (int j = 0; j < 4; ++j) {
            const long long row = rbase + 2 * j + half;
            const bool ok = (row < N);
            float4 e = ok ? emb4[row * HD4 + col] : make_float4(0, 0, 0, 0);
            int    s = ok ? seg[row] : 0;
            float4 w = ((const float4*)sd)[(long long)s * HD4 + col];
            float2 acc;
            acc.x = e.x * w.x + e.y * w.y + e.z * w.z + e.w * w.w;
            acc.y = e.x * e.x + e.y * e.y + e.z * e.z + e.w * e.w;
            #pragma unroll
            for (int m = 16; m >= 1; m >>= 1) {
                const float2 o = shfl_xor_f2(acc, m);
                acc.x += o.x; acc.y += o.y;
            }
            if (ok && col == 0)
                out[row] = acc.x / fmaxf(sqrtf(acc.y), NEPS);
        }
    }
}

// ---- fallback (no workspace): R1 kernel ----
__global__ __launch_bounds__(256) void sim_fallback(
    const float* __restrict__ emb, const float* __restrict__ summary,
    const int* __restrict__ ptr, const float* __restrict__ dvec,
    const float* __restrict__ scale, float* __restrict__ out, int N, int B)
{
    const int tid  = blockIdx.x * blockDim.x + threadIdx.x;
    const int lane = tid & 63;
    const int half = lane >> 5;
    const int l    = lane & 31;
    const long long row = (long long)(tid >> 6) * 2 + half;
    if (row >= N) return;
    int lo = 0, hi = B;
    while (lo < hi) {
        int mid = (lo + hi) >> 1;
        if (ptr[1 + mid] <= (int)row) lo = mid + 1; else hi = mid;
    }
    const float4* e4 = (const float4*)(emb + row * HDIM);
    const float4* s4 = (const float4*)(summary + (long long)lo * HDIM);
    const float4* d4 = (const float4*)dvec;
    const float4 e = e4[l], s = s4[l], dd = d4[l];
    float sumsq = e.x*e.x + e.y*e.y + e.z*e.z + e.w*e.w;
    float dot   = e.x*dd.x*s.x + e.y*dd.y*s.y + e.z*dd.z*s.z + e.w*dd.w*s.w;
    #pragma unroll
    for (int m = 16; m >= 1; m >>= 1) {
        sumsq += __shfl_xor(sumsq, m, 64);
        dot   += __shfl_xor(dot,   m, 64);
    }
    if (l == 0)
        out[row] = dot / fmaxf(sqrtf(sumsq), NEPS) * scale[0];
}

extern "C" void kernel_launch(void* const* d_in, const int* in_sizes, int n_in,
                              void* d_out, int out_size, void* d_ws, size_t ws_size,
                              hipStream_t stream) {
    const float* emb     = (const float*)d_in[0];
    const float* summary = (const float*)d_in[1];
    const int*   ptr     = (const int*)d_in[2];
    const float* dvec    = (const float*)d_in[3];
    const float* scale   = (const float*)d_in[4];
    float*       out     = (float*)d_out;

    const int Hn = in_sizes[3];           // 128
    const int N  = in_sizes[0] / Hn;      // 1048576
    const int B  = in_sizes[1] / Hn;      // 1024

    const size_t sd_bytes  = (size_t)B * Hn * sizeof(float);   // 512 KB
    const size_t seg_bytes = (size_t)N * sizeof(int);          // 4 MB

    if (ws_size >= sd_bytes + seg_bytes) {
        float* sd  = (float*)d_ws;
        int*   seg = (int*)((char*)d_ws + sd_bytes);

        prep<<<B, 256, 0, stream>>>(ptr, summary, dvec, scale, sd, seg);
        // 8 rows per wave, 4 waves per block -> 32 rows per block
        const int blocks = (N + 31) / 32;
        sim_main<<<blocks, 256, 0, stream>>>((const float4*)emb, sd, seg,
                                             out, N);
    } else {
        sim_fallback<<<(N + 7) / 8, 256, 0, stream>>>(emb, summary, ptr, dvec,
                                                      scale, out, N, B);
    }
}